// Round 13
// baseline (169.006 us; speedup 1.0000x reference)
//
#include <hip/hip_runtime.h>
#include <hip/hip_bf16.h>

#define B_    8
#define CH    512
#define NPIX  1024
#define HEADS 8
#define HD    64

typedef unsigned short ushortT;
typedef __attribute__((ext_vector_type(8))) short frag8;   // 8 bf16 (4 VGPRs)
typedef __attribute__((ext_vector_type(4))) float f32x4;   // MFMA C/D

__device__ __forceinline__ ushortT f2u(float f) {
    __hip_bfloat16 h = __float2bfloat16(f);
    return *(ushortT*)&h;
}
__device__ __forceinline__ unsigned pack2(float lo, float hi) {
    return (unsigned)f2u(lo) | ((unsigned)f2u(hi) << 16);
}

// Async global->LDS, 16B per lane. LDS dest is wave-uniform base + lane*16.
__device__ __forceinline__ void gload16(const ushortT* g, ushortT* lds) {
    __builtin_amdgcn_global_load_lds(
        (const __attribute__((address_space(1))) unsigned int*)g,
        (__attribute__((address_space(3))) unsigned int*)lds, 16, 0, 0);
}

// Stage R rows x 64 bf16 cols from global (row stride srow elems) into linear
// LDS [R][64] by 4 waves. XOR-swizzle: LDS(r, chunk) holds global(r, chunk^(r&7))
// [chunk = 16B]. Read of global (r,c) = LDS chunk c^(r&7) (T2, involution).
template<int R>
__device__ __forceinline__ void stage_swz(ushortT* lds, const ushortT* src,
                                          size_t srow, int wave, int lane) {
    const int rl = lane >> 3, ch = lane & 7;
#pragma unroll
    for (int j = 0; j < R / 32; ++j) {
        const int r = wave * (R / 4) + j * 8 + rl;
        gload16(src + (size_t)r * srow + ((ch ^ (r & 7)) * 8),
                lds + (wave * (R / 4) + j * 8) * 64);
    }
}

// Same, for 8-wave (512-thread) blocks staging a 64-row tile: 1 gload16/wave.
__device__ __forceinline__ void stage_swz8(ushortT* lds, const ushortT* src,
                                           size_t srow, int wave, int lane) {
    const int rl = lane >> 3, ch = lane & 7;
    const int r = wave * 8 + rl;
    gload16(src + (size_t)r * srow + ((ch ^ (r & 7)) * 8),
            lds + (wave * 8) * 64);
}

// Read one 16B fragment of global (row, kq*8..kq*8+7) from a swizzled tile.
__device__ __forceinline__ frag8 frd(const ushortT* lds, int row, int kq) {
    return *(const frag8*)&lds[row * 64 + ((kq ^ (row & 7)) * 8)];
}

// Both fp32->bf16 transposes + all 4 weight conversions in one launch.
// z in [0,16): transpose (b = z&7, which = z>>3).  z in [16,20): W cvt.
__global__ __launch_bounds__(256) void cvt_transpose(
    const float* __restrict__ Xc, const float* __restrict__ Xs,
    ushortT* __restrict__ XTc, ushortT* __restrict__ XTs,
    const float* __restrict__ Wq, const float* __restrict__ Wk,
    const float* __restrict__ Wv, const float* __restrict__ Wo,
    ushortT* __restrict__ Wb)
{
    if (blockIdx.z >= 16) {   // weight fp32 -> bf16, once
        const int w = blockIdx.z - 16;
        const float* Wsrc = (w == 0) ? Wq : (w == 1) ? Wk : (w == 2) ? Wv : Wo;
        ushortT* Wdst = Wb + (size_t)w * CH * CH;
        const int base = (blockIdx.y * 16 + blockIdx.x) * 2048 + threadIdx.x * 8;
        float4 f0 = *(const float4*)&Wsrc[base];
        float4 f1 = *(const float4*)&Wsrc[base + 4];
        ushortT t[8];
        t[0]=f2u(f0.x); t[1]=f2u(f0.y); t[2]=f2u(f0.z); t[3]=f2u(f0.w);
        t[4]=f2u(f1.x); t[5]=f2u(f1.y); t[6]=f2u(f1.z); t[7]=f2u(f1.w);
        *(uint4*)&Wdst[base] = *(uint4*)t;
        return;
    }
    __shared__ __align__(16) ushortT T[64 * 72];   // [n][c], stride 72
    const int n0 = blockIdx.x * 64;
    const int c0 = blockIdx.y * 64;
    const int b  = blockIdx.z & 7;
    const int which = blockIdx.z >> 3;
    const float* X = which ? Xs : Xc;
    ushortT* XT    = which ? XTs : XTc;
    const int tid = threadIdx.x;
#pragma unroll
    for (int it = 0; it < 2; ++it) {
        int idx = tid + it * 256;          // 512 items: 32 c-pairs x 16 n-quads
        int cp = idx >> 4;
        int nq = (idx & 15) * 4;
        const float* s0 = &X[((size_t)b * CH + c0 + 2 * cp) * NPIX + n0 + nq];
        float4 f0 = *(const float4*)s0;
        float4 f1 = *(const float4*)(s0 + NPIX);
        *(unsigned*)&T[(nq + 0) * 72 + 2 * cp] = pack2(f0.x, f1.x);
        *(unsigned*)&T[(nq + 1) * 72 + 2 * cp] = pack2(f0.y, f1.y);
        *(unsigned*)&T[(nq + 2) * 72 + 2 * cp] = pack2(f0.z, f1.z);
        *(unsigned*)&T[(nq + 3) * 72 + 2 * cp] = pack2(f0.w, f1.w);
    }
    __syncthreads();
#pragma unroll
    for (int it = 0; it < 2; ++it) {
        int idx = tid + it * 256;
        int n  = idx >> 3;
        int cq = (idx & 7) * 8;
        *(uint4*)&XT[((size_t)b * NPIX + n0 + n) * CH + c0 + cq] =
            *(const uint4*)&T[n * 72 + cq];
    }
}

// ---------------------------------------------------------------------------
// m97-structure GEMM: block tile 128m x 128n, BK=64, single 32KB LDS buffer,
// 2 barriers per K-step. 4 waves, each 64x64 output. 3 blocks/CU.
// MODE 0: bf16 natural [b][o][n]; MODE 1: bf16 transposed [b][n][o].
// ---------------------------------------------------------------------------
template<int MODE>
__device__ __forceinline__ void proj128_body(
    ushortT* As, ushortT* Bs,   // [128*64] each, swizzled
    const ushortT* __restrict__ Wb, const ushortT* __restrict__ XT,
    const float* __restrict__ bias, void* __restrict__ Yv,
    int b, int n0, int m0)
{
    const int tid  = threadIdx.x;
    const int wave = tid >> 6, lane = tid & 63;
    const int quad = lane >> 4, l16 = lane & 15;
    const int wm = (wave & 1) * 64, wn = (wave >> 1) * 64;

    const ushortT* Wblk = Wb + (size_t)m0 * CH;
    const ushortT* Xblk = XT + ((size_t)b * NPIX + n0) * CH;

    f32x4 acc[4][4];
#pragma unroll
    for (int i = 0; i < 4; ++i)
#pragma unroll
        for (int j = 0; j < 4; ++j) acc[i][j] = (f32x4){0.f, 0.f, 0.f, 0.f};

    for (int s = 0; s < 8; ++s) {
        if (s) __syncthreads();               // all waves done reading buffer
        stage_swz<128>(As, Wblk + s * 64, CH, wave, lane);
        stage_swz<128>(Bs, Xblk + s * 64, CH, wave, lane);
        __syncthreads();                      // drains vmcnt: tile staged
#pragma unroll
        for (int ks = 0; ks < 2; ++ks) {
            frag8 af[4], bf[4];
#pragma unroll
            for (int i = 0; i < 4; ++i)
                af[i] = frd(As, wm + i * 16 + l16, ks * 4 + quad);
#pragma unroll
            for (int j = 0; j < 4; ++j)
                bf[j] = frd(Bs, wn + j * 16 + l16, ks * 4 + quad);
#pragma unroll
            for (int i = 0; i < 4; ++i)
#pragma unroll
                for (int j = 0; j < 4; ++j)
                    acc[i][j] = __builtin_amdgcn_mfma_f32_16x16x32_bf16(
                        af[i], bf[j], acc[i][j], 0, 0, 0);
        }
    }

#pragma unroll
    for (int i = 0; i < 4; ++i) {
        const int om0 = m0 + wm + i * 16 + quad * 4;
#pragma unroll
        for (int j = 0; j < 4; ++j) {
            const int on = n0 + wn + j * 16 + l16;
            if (MODE == 1) {
                ushort4 v;
                v.x = f2u(acc[i][j][0] + bias[om0 + 0]);
                v.y = f2u(acc[i][j][1] + bias[om0 + 1]);
                v.z = f2u(acc[i][j][2] + bias[om0 + 2]);
                v.w = f2u(acc[i][j][3] + bias[om0 + 3]);
                *(ushort4*)&((ushortT*)Yv)[((size_t)b * NPIX + on) * CH + om0] = v;
            } else {
#pragma unroll
                for (int r = 0; r < 4; ++r) {
                    const int om = om0 + r;
                    ((ushortT*)Yv)[((size_t)b * CH + om) * NPIX + on] =
                        f2u(acc[i][j][r] + bias[om]);
                }
            }
        }
    }
}

// Fused Q+K+V projections. z = which*8 + b; 0=Q(selfT),1=K(crossT),2=V(crossT).
__global__ __launch_bounds__(256, 3) void qkv_proj(
    const ushortT* __restrict__ Wqb, const ushortT* __restrict__ Wkb,
    const ushortT* __restrict__ Wvb,
    const ushortT* __restrict__ selfT, const ushortT* __restrict__ crossT,
    const float* __restrict__ bq, const float* __restrict__ bk,
    const float* __restrict__ bv,
    ushortT* __restrict__ Qt, ushortT* __restrict__ Kt, ushortT* __restrict__ Vn)
{
    __shared__ __align__(16) ushortT As[128 * 64];
    __shared__ __align__(16) ushortT Bs[128 * 64];
    const int which = blockIdx.z >> 3;
    const int b     = blockIdx.z & 7;
    const int n0 = blockIdx.x * 128, m0 = blockIdx.y * 128;
    if (which == 2)
        proj128_body<0>(As, Bs, Wvb, crossT, bv, Vn, b, n0, m0);
    else if (which == 1)
        proj128_body<1>(As, Bs, Wkb, crossT, bk, Kt, b, n0, m0);
    else
        proj128_body<1>(As, Bs, Wqb, selfT, bq, Qt, b, n0, m0);
}

// ---------------------------------------------------------------------------
// out_proj: 64m x 128n, double-buffered, 1 barrier/step, fp32 + residual
// epilogue. 512 blocks = 2/CU.
// ---------------------------------------------------------------------------
__global__ __launch_bounds__(256, 3) void out_proj(
    const ushortT* __restrict__ Wob, const ushortT* __restrict__ Ot,
    const float* __restrict__ bo, float* __restrict__ Y,
    const float* __restrict__ residual)
{
    __shared__ __align__(16) ushortT As[2 * 64 * 64];
    __shared__ __align__(16) ushortT Bs[2 * 128 * 64];
    const int b = blockIdx.z;
    const int n0 = blockIdx.x * 128, m0 = blockIdx.y * 64;
    const int tid  = threadIdx.x;
    const int wave = tid >> 6, lane = tid & 63;
    const int quad = lane >> 4, l16 = lane & 15;
    const int wm = (wave & 1) * 32, wn = (wave >> 1) * 64;

    const ushortT* Wblk = Wob + (size_t)m0 * CH;
    const ushortT* Xblk = Ot + ((size_t)b * NPIX + n0) * CH;

    f32x4 acc[2][4];
#pragma unroll
    for (int i = 0; i < 2; ++i)
#pragma unroll
        for (int j = 0; j < 4; ++j) acc[i][j] = (f32x4){0.f, 0.f, 0.f, 0.f};

    stage_swz<64>(As, Wblk, CH, wave, lane);
    stage_swz<128>(Bs, Xblk, CH, wave, lane);
    __syncthreads();

    int buf = 0;
    for (int s = 0; s < 8; ++s) {
        if (s < 7) {
            stage_swz<64>(As + (buf ^ 1) * 64 * 64,  Wblk + (s + 1) * 64, CH, wave, lane);
            stage_swz<128>(Bs + (buf ^ 1) * 128 * 64, Xblk + (s + 1) * 64, CH, wave, lane);
        }
        const ushortT* A  = As + buf * 64 * 64;
        const ushortT* Bp = Bs + buf * 128 * 64;
        frag8 af[2][2], bfr[4][2];
#pragma unroll
        for (int ks = 0; ks < 2; ++ks) {
#pragma unroll
            for (int i = 0; i < 2; ++i)
                af[i][ks] = frd(A, wm + i * 16 + l16, ks * 4 + quad);
#pragma unroll
            for (int j = 0; j < 4; ++j)
                bfr[j][ks] = frd(Bp, wn + j * 16 + l16, ks * 4 + quad);
        }
#pragma unroll
        for (int ks = 0; ks < 2; ++ks)
#pragma unroll
            for (int i = 0; i < 2; ++i)
#pragma unroll
                for (int j = 0; j < 4; ++j)
                    acc[i][j] = __builtin_amdgcn_mfma_f32_16x16x32_bf16(
                        af[i][ks], bfr[j][ks], acc[i][j], 0, 0, 0);
        __syncthreads();
        buf ^= 1;
    }

#pragma unroll
    for (int i = 0; i < 2; ++i) {
        const int om0 = m0 + wm + i * 16 + quad * 4;
#pragma unroll
        for (int j = 0; j < 4; ++j) {
            const int on = n0 + wn + j * 16 + l16;
#pragma unroll
            for (int r = 0; r < 4; ++r) {
                const int om = om0 + r;
                const size_t idx = ((size_t)b * CH + om) * NPIX + on;
                Y[idx] = acc[i][j][r] + bo[om] + residual[idx];
            }
        }
    }
}

// ---------------------------------------------------------------------------
// Flash attention, SPLIT-KV over 2 parts. No-max softmax is exactly splittable:
// part p computes unnormalized O_p, l_p over KV tiles p*8..p*8+7; combine does
// O = (O0+O1)/(l0+l1). Grid (64, 8, 2) = 1024 blocks -> 3 blocks/CU (24
// waves/CU vs 16 before) with half the work per block — attacks the measured
// lever (waves/CU: 16w:158.9 < 12w:166.5 < 8w:~173). launch_bounds(512,6)
// caps VGPR ~85 to guarantee 3/CU residency. K/V traffic unchanged (disjoint
// halves); costs +32MB f32 partials + combine pass. Per-tile body identical
// to the r5/r12 plateau kernel (dbuf gload_lds, 1 barrier/tile, setprio).
// ---------------------------------------------------------------------------
__global__ __launch_bounds__(512, 6) void attn_mfma(
    const ushortT* __restrict__ Qt, const ushortT* __restrict__ Kt,
    const ushortT* __restrict__ V, float* __restrict__ Op,
    float* __restrict__ lp)
{
    __shared__ __align__(16) ushortT Ks[2][64 * 64];   // [m][d] swizzled
    __shared__ __align__(16) ushortT Vs[2][64 * 64];   // [d][m] swizzled
    __shared__ __align__(16) ushortT Ps[128 * 72];     // [n][m], wave-private rows
    const int bh = blockIdx.x;          // 0..63
    const int n0 = blockIdx.y * 128;
    const int part = blockIdx.z;        // 0,1: KV tiles part*8 .. part*8+7
    const int t0 = part * 8;
    const int b  = bh >> 3, h = bh & 7;
    const int tid  = threadIdx.x;
    const int wave = tid >> 6, lane = tid & 63;
    const int quad = lane >> 4, l16 = lane & 15;
    const size_t qrow  = (size_t)b * NPIX;
    const size_t vbase = ((size_t)b * CH + h * HD) * NPIX;
    const int nw = n0 + wave * 16;      // this wave's 16 query rows

    // Q fragments in registers, loaded once from global
    frag8 aq[2];   // [ks]
#pragma unroll
    for (int ks = 0; ks < 2; ++ks)
        aq[ks] = *(const frag8*)&Qt[(qrow + nw + l16) * CH
                                    + h * HD + ks * 32 + quad * 8];
    frag8 ones;
#pragma unroll
    for (int i = 0; i < 8; ++i) ones[i] = (short)0x3F80;   // bf16 1.0

    f32x4 oacc[4], lacc;
    lacc = (f32x4){0.f, 0.f, 0.f, 0.f};
#pragma unroll
    for (int dt = 0; dt < 4; ++dt) oacc[dt] = (f32x4){0.f, 0.f, 0.f, 0.f};

    // exp(s*0.125) == exp2(s * 0.125*log2(e)): fold scale+log2e into one mul
    const float SC2 = 0.18033688011112042f;

    stage_swz8(Ks[0], Kt + (qrow + t0 * 64) * CH + h * HD, CH, wave, lane);
    stage_swz8(Vs[0], V + vbase + t0 * 64, NPIX, wave, lane);
    __syncthreads();

    int buf = 0;
    for (int tt = 0; tt < 8; ++tt) {
        const int t = t0 + tt;
        if (tt + 1 < 8) {   // async prefetch next K/V tile
            stage_swz8(Ks[buf ^ 1], Kt + (qrow + (t + 1) * 64) * CH + h * HD,
                       CH, wave, lane);
            stage_swz8(Vs[buf ^ 1], V + vbase + (t + 1) * 64, NPIX, wave, lane);
        }

        // S^T = K Q^T; P = exp2(S*SC2) packed 4-wide into Ps[n][m]
#pragma unroll
        for (int mt = 0; mt < 4; ++mt) {
            f32x4 st = (f32x4){0.f, 0.f, 0.f, 0.f};
            __builtin_amdgcn_s_setprio(1);
#pragma unroll
            for (int ks = 0; ks < 2; ++ks) {
                frag8 bk = frd(Ks[buf], mt * 16 + l16, ks * 4 + quad);
                st = __builtin_amdgcn_mfma_f32_16x16x32_bf16(bk, aq[ks], st, 0, 0, 0);
            }
            __builtin_amdgcn_s_setprio(0);
            ushort4 p;
            p.x = f2u(exp2f(st[0] * SC2)); p.y = f2u(exp2f(st[1] * SC2));
            p.z = f2u(exp2f(st[2] * SC2)); p.w = f2u(exp2f(st[3] * SC2));
            *(ushort4*)&Ps[(wave * 16 + l16) * 72 + mt * 16 + quad * 4] = p;
        }
        // Ps rows are wave-private: in-wave lgkmcnt ordering suffices, no barrier.

        frag8 ap[2];
#pragma unroll
        for (int ks = 0; ks < 2; ++ks)
            ap[ks] = *(const frag8*)&Ps[(wave * 16 + l16) * 72 + ks * 32 + quad * 8];

        __builtin_amdgcn_s_setprio(1);
        // l += P @ ones
#pragma unroll
        for (int ks = 0; ks < 2; ++ks)
            lacc = __builtin_amdgcn_mfma_f32_16x16x32_bf16(ap[ks], ones, lacc, 0, 0, 0);
        // O += P V
#pragma unroll
        for (int dt = 0; dt < 4; ++dt)
#pragma unroll
            for (int ks = 0; ks < 2; ++ks) {
                frag8 bv = frd(Vs[buf], dt * 16 + l16, ks * 4 + quad);
                oacc[dt] = __builtin_amdgcn_mfma_f32_16x16x32_bf16(ap[ks], bv, oacc[dt], 0, 0, 0);
            }
        __builtin_amdgcn_s_setprio(0);

        __syncthreads();   // drains vmcnt: next buffer staged; all waves done with cur
        buf ^= 1;
    }

    // epilogue: write unnormalized partial O (f32) and partial l
    float* Orow = Op + ((size_t)(part * B_ + b) * NPIX) * CH;
#pragma unroll
    for (int r = 0; r < 4; ++r) {
        const int n = nw + quad * 4 + r;
#pragma unroll
        for (int dt = 0; dt < 4; ++dt)
            Orow[(size_t)n * CH + h * HD + dt * 16 + l16] = oacc[dt][r];
        if (l16 == 0)
            lp[((size_t)(part * B_ + b) * HEADS + h) * NPIX + n] = lacc[r];
    }
}

// Combine: O = (O0 + O1) / (l0 + l1), bf16 out to Ot[b][n][c].
// 4096 blocks x 256 threads, 4 channels/thread (float4 loads, ushort4 store).
__global__ __launch_bounds__(256) void attn_combine(
    const float* __restrict__ Op, const float* __restrict__ lp,
    ushortT* __restrict__ Ot)
{
    const size_t NELT = (size_t)B_ * CH * NPIX;
    const size_t idx = ((size_t)blockIdx.x * 256 + threadIdx.x) * 4;
    const int c  = (int)(idx % CH);
    const size_t bn = idx / CH;                 // b*NPIX + n
    const int b = (int)(bn / NPIX), n = (int)(bn % NPIX);
    const int h = c >> 6;
    const float l0 = lp[((size_t)(0 * B_ + b) * HEADS + h) * NPIX + n];
    const float l1 = lp[((size_t)(1 * B_ + b) * HEADS + h) * NPIX + n];
    const float inv = __builtin_amdgcn_rcpf(l0 + l1);
    const float4 o0 = *(const float4*)&Op[bn * CH + c];
    const float4 o1 = *(const float4*)&Op[NELT + bn * CH + c];
    ushort4 v;
    v.x = f2u((o0.x + o1.x) * inv); v.y = f2u((o0.y + o1.y) * inv);
    v.z = f2u((o0.z + o1.z) * inv); v.w = f2u((o0.w + o1.w) * inv);
    *(ushort4*)&Ot[bn * CH + c] = v;
}

// Sentinel: ws too small -> zero output (absmax == max|ref| ~5.0, distinguishable)
__global__ void zero_out_kernel(float* o, int n) {
    int i = blockIdx.x * 256 + threadIdx.x;
    if (i < n) o[i] = 0.f;
}

extern "C" void kernel_launch(void* const* d_in, const int* in_sizes, int n_in,
                              void* d_out, int out_size, void* d_ws, size_t ws_size,
                              hipStream_t stream) {
    const float* self  = (const float*)d_in[0];
    const float* cross = (const float*)d_in[1];
    const float* Wq = (const float*)d_in[2];
    const float* bq = (const float*)d_in[3];
    const float* Wk = (const float*)d_in[4];
    const float* bk = (const float*)d_in[5];
    const float* Wv = (const float*)d_in[6];
    const float* bv = (const float*)d_in[7];
    const float* Wo = (const float*)d_in[8];
    const float* bo = (const float*)d_in[9];

    const size_t NELT = (size_t)B_ * CH * NPIX;   // 4,194,304
    const size_t WELT = (size_t)CH * CH;          //   262,144
    const size_t LELT = (size_t)B_ * HEADS * NPIX; // 65,536

    // ws: Qt(8M)|Kt(8M)|Vn(8M)|Wb(2M) bf16 + Opart(32M)|lpart(0.5M) f32 = 58.5 MiB
    const size_t need = (3 * NELT + 4 * WELT) * sizeof(ushortT)
                      + (2 * NELT + 2 * LELT) * sizeof(float);
    if (ws_size < need) {
        const size_t n = (size_t)B_ * CH * NPIX;
        zero_out_kernel<<<(int)((n + 255) / 256), 256, 0, stream>>>((float*)d_out, (int)n);
        return;
    }

    // d_out (16 MiB) doubles as scratch: [crossT 8MiB | selfT 8MiB]
    ushortT* crossT = (ushortT*)d_out;
    ushortT* selfT  = (ushortT*)d_out + NELT;
    ushortT* Qt  = (ushortT*)d_ws;            // [b][n][c]
    ushortT* Kt  = Qt + NELT;                 // [b][n][c]
    ushortT* Vn  = Kt + NELT;                 // [b][c][n]
    ushortT* Wb  = Vn + NELT;                 // 4x [512][512] bf16
    ushortT* Wqb = Wb;
    ushortT* Wkb = Wb + WELT;
    ushortT* Wvb = Wb + 2 * WELT;
    ushortT* Wob = Wb + 3 * WELT;
    float* Opart = (float*)(Wb + 4 * WELT);   // [2][b][n][c] f32
    float* lpart = Opart + 2 * NELT;          // [2][b][h][n] f32

    dim3 bb(256);
    cvt_transpose<<<dim3(16, 8, 20), bb, 0, stream>>>(cross, self, crossT, selfT,
                                                      Wq, Wk, Wv, Wo, Wb);
    qkv_proj<<<dim3(8, 4, 24), bb, 0, stream>>>(Wqb, Wkb, Wvb, selfT, crossT,
                                                bq, bk, bv, Qt, Kt, Vn);
    attn_mfma<<<dim3(64, 8, 2), dim3(512), 0, stream>>>(Qt, Kt, Vn, Opart, lpart);
    attn_combine<<<dim3(4096), bb, 0, stream>>>(Opart, lpart, Qt);
    out_proj<<<dim3(8, 8, B_), bb, 0, stream>>>(Wob, Qt, bo, (float*)d_out, self);
}

// Round 14
// 158.903 us; speedup vs baseline: 1.0636x; 1.0636x over previous
//
#include <hip/hip_runtime.h>
#include <hip/hip_bf16.h>

#define B_    8
#define CH    512
#define NPIX  1024
#define HEADS 8
#define HD    64

typedef unsigned short ushortT;
typedef __attribute__((ext_vector_type(8))) short frag8;   // 8 bf16 (4 VGPRs)
typedef __attribute__((ext_vector_type(4))) float f32x4;   // MFMA C/D

__device__ __forceinline__ ushortT f2u(float f) {
    __hip_bfloat16 h = __float2bfloat16(f);
    return *(ushortT*)&h;
}
__device__ __forceinline__ unsigned pack2(float lo, float hi) {
    return (unsigned)f2u(lo) | ((unsigned)f2u(hi) << 16);
}

// Async global->LDS, 16B per lane. LDS dest is wave-uniform base + lane*16.
__device__ __forceinline__ void gload16(const ushortT* g, ushortT* lds) {
    __builtin_amdgcn_global_load_lds(
        (const __attribute__((address_space(1))) unsigned int*)g,
        (__attribute__((address_space(3))) unsigned int*)lds, 16, 0, 0);
}

// Stage R rows x 64 bf16 cols from global (row stride srow elems) into linear
// LDS [R][64] by 4 waves. XOR-swizzle: LDS(r, chunk) holds global(r, chunk^(r&7))
// [chunk = 16B]. Read of global (r,c) = LDS chunk c^(r&7) (T2, involution).
template<int R>
__device__ __forceinline__ void stage_swz(ushortT* lds, const ushortT* src,
                                          size_t srow, int wave, int lane) {
    const int rl = lane >> 3, ch = lane & 7;
#pragma unroll
    for (int j = 0; j < R / 32; ++j) {
        const int r = wave * (R / 4) + j * 8 + rl;
        gload16(src + (size_t)r * srow + ((ch ^ (r & 7)) * 8),
                lds + (wave * (R / 4) + j * 8) * 64);
    }
}

// Same, for 8-wave (512-thread) blocks staging a 64-row tile: 1 gload16/wave.
__device__ __forceinline__ void stage_swz8(ushortT* lds, const ushortT* src,
                                           size_t srow, int wave, int lane) {
    const int rl = lane >> 3, ch = lane & 7;
    const int r = wave * 8 + rl;
    gload16(src + (size_t)r * srow + ((ch ^ (r & 7)) * 8),
            lds + (wave * 8) * 64);
}

// Read one 16B fragment of global (row, kq*8..kq*8+7) from a swizzled tile.
__device__ __forceinline__ frag8 frd(const ushortT* lds, int row, int kq) {
    return *(const frag8*)&lds[row * 64 + ((kq ^ (row & 7)) * 8)];
}

// Both fp32->bf16 transposes + all 4 weight conversions in one launch.
// z in [0,16): transpose (b = z&7, which = z>>3).  z in [16,20): W cvt.
__global__ __launch_bounds__(256) void cvt_transpose(
    const float* __restrict__ Xc, const float* __restrict__ Xs,
    ushortT* __restrict__ XTc, ushortT* __restrict__ XTs,
    const float* __restrict__ Wq, const float* __restrict__ Wk,
    const float* __restrict__ Wv, const float* __restrict__ Wo,
    ushortT* __restrict__ Wb)
{
    if (blockIdx.z >= 16) {   // weight fp32 -> bf16, once
        const int w = blockIdx.z - 16;
        const float* Wsrc = (w == 0) ? Wq : (w == 1) ? Wk : (w == 2) ? Wv : Wo;
        ushortT* Wdst = Wb + (size_t)w * CH * CH;
        const int base = (blockIdx.y * 16 + blockIdx.x) * 2048 + threadIdx.x * 8;
        float4 f0 = *(const float4*)&Wsrc[base];
        float4 f1 = *(const float4*)&Wsrc[base + 4];
        ushortT t[8];
        t[0]=f2u(f0.x); t[1]=f2u(f0.y); t[2]=f2u(f0.z); t[3]=f2u(f0.w);
        t[4]=f2u(f1.x); t[5]=f2u(f1.y); t[6]=f2u(f1.z); t[7]=f2u(f1.w);
        *(uint4*)&Wdst[base] = *(uint4*)t;
        return;
    }
    __shared__ __align__(16) ushortT T[64 * 72];   // [n][c], stride 72
    const int n0 = blockIdx.x * 64;
    const int c0 = blockIdx.y * 64;
    const int b  = blockIdx.z & 7;
    const int which = blockIdx.z >> 3;
    const float* X = which ? Xs : Xc;
    ushortT* XT    = which ? XTs : XTc;
    const int tid = threadIdx.x;
#pragma unroll
    for (int it = 0; it < 2; ++it) {
        int idx = tid + it * 256;          // 512 items: 32 c-pairs x 16 n-quads
        int cp = idx >> 4;
        int nq = (idx & 15) * 4;
        const float* s0 = &X[((size_t)b * CH + c0 + 2 * cp) * NPIX + n0 + nq];
        float4 f0 = *(const float4*)s0;
        float4 f1 = *(const float4*)(s0 + NPIX);
        *(unsigned*)&T[(nq + 0) * 72 + 2 * cp] = pack2(f0.x, f1.x);
        *(unsigned*)&T[(nq + 1) * 72 + 2 * cp] = pack2(f0.y, f1.y);
        *(unsigned*)&T[(nq + 2) * 72 + 2 * cp] = pack2(f0.z, f1.z);
        *(unsigned*)&T[(nq + 3) * 72 + 2 * cp] = pack2(f0.w, f1.w);
    }
    __syncthreads();
#pragma unroll
    for (int it = 0; it < 2; ++it) {
        int idx = tid + it * 256;
        int n  = idx >> 3;
        int cq = (idx & 7) * 8;
        *(uint4*)&XT[((size_t)b * NPIX + n0 + n) * CH + c0 + cq] =
            *(const uint4*)&T[n * 72 + cq];
    }
}

// ---------------------------------------------------------------------------
// m97-structure GEMM: block tile 128m x 128n, BK=64, single 32KB LDS buffer,
// 2 barriers per K-step. 4 waves, each 64x64 output. 3 blocks/CU.
// MODE 0: bf16 natural [b][o][n]; MODE 1: bf16 transposed [b][n][o].
// ---------------------------------------------------------------------------
template<int MODE>
__device__ __forceinline__ void proj128_body(
    ushortT* As, ushortT* Bs,   // [128*64] each, swizzled
    const ushortT* __restrict__ Wb, const ushortT* __restrict__ XT,
    const float* __restrict__ bias, void* __restrict__ Yv,
    int b, int n0, int m0)
{
    const int tid  = threadIdx.x;
    const int wave = tid >> 6, lane = tid & 63;
    const int quad = lane >> 4, l16 = lane & 15;
    const int wm = (wave & 1) * 64, wn = (wave >> 1) * 64;

    const ushortT* Wblk = Wb + (size_t)m0 * CH;
    const ushortT* Xblk = XT + ((size_t)b * NPIX + n0) * CH;

    f32x4 acc[4][4];
#pragma unroll
    for (int i = 0; i < 4; ++i)
#pragma unroll
        for (int j = 0; j < 4; ++j) acc[i][j] = (f32x4){0.f, 0.f, 0.f, 0.f};

    for (int s = 0; s < 8; ++s) {
        if (s) __syncthreads();               // all waves done reading buffer
        stage_swz<128>(As, Wblk + s * 64, CH, wave, lane);
        stage_swz<128>(Bs, Xblk + s * 64, CH, wave, lane);
        __syncthreads();                      // drains vmcnt: tile staged
#pragma unroll
        for (int ks = 0; ks < 2; ++ks) {
            frag8 af[4], bf[4];
#pragma unroll
            for (int i = 0; i < 4; ++i)
                af[i] = frd(As, wm + i * 16 + l16, ks * 4 + quad);
#pragma unroll
            for (int j = 0; j < 4; ++j)
                bf[j] = frd(Bs, wn + j * 16 + l16, ks * 4 + quad);
#pragma unroll
            for (int i = 0; i < 4; ++i)
#pragma unroll
                for (int j = 0; j < 4; ++j)
                    acc[i][j] = __builtin_amdgcn_mfma_f32_16x16x32_bf16(
                        af[i], bf[j], acc[i][j], 0, 0, 0);
        }
    }

#pragma unroll
    for (int i = 0; i < 4; ++i) {
        const int om0 = m0 + wm + i * 16 + quad * 4;
#pragma unroll
        for (int j = 0; j < 4; ++j) {
            const int on = n0 + wn + j * 16 + l16;
            if (MODE == 1) {
                ushort4 v;
                v.x = f2u(acc[i][j][0] + bias[om0 + 0]);
                v.y = f2u(acc[i][j][1] + bias[om0 + 1]);
                v.z = f2u(acc[i][j][2] + bias[om0 + 2]);
                v.w = f2u(acc[i][j][3] + bias[om0 + 3]);
                *(ushort4*)&((ushortT*)Yv)[((size_t)b * NPIX + on) * CH + om0] = v;
            } else {
#pragma unroll
                for (int r = 0; r < 4; ++r) {
                    const int om = om0 + r;
                    ((ushortT*)Yv)[((size_t)b * CH + om) * NPIX + on] =
                        f2u(acc[i][j][r] + bias[om]);
                }
            }
        }
    }
}

// Fused Q+K+V projections. z = which*8 + b; 0=Q(selfT),1=K(crossT),2=V(crossT).
__global__ __launch_bounds__(256, 3) void qkv_proj(
    const ushortT* __restrict__ Wqb, const ushortT* __restrict__ Wkb,
    const ushortT* __restrict__ Wvb,
    const ushortT* __restrict__ selfT, const ushortT* __restrict__ crossT,
    const float* __restrict__ bq, const float* __restrict__ bk,
    const float* __restrict__ bv,
    ushortT* __restrict__ Qt, ushortT* __restrict__ Kt, ushortT* __restrict__ Vn)
{
    __shared__ __align__(16) ushortT As[128 * 64];
    __shared__ __align__(16) ushortT Bs[128 * 64];
    const int which = blockIdx.z >> 3;
    const int b     = blockIdx.z & 7;
    const int n0 = blockIdx.x * 128, m0 = blockIdx.y * 128;
    if (which == 2)
        proj128_body<0>(As, Bs, Wvb, crossT, bv, Vn, b, n0, m0);
    else if (which == 1)
        proj128_body<1>(As, Bs, Wkb, crossT, bk, Kt, b, n0, m0);
    else
        proj128_body<1>(As, Bs, Wqb, selfT, bq, Qt, b, n0, m0);
}

// ---------------------------------------------------------------------------
// out_proj: 64m x 128n, double-buffered, 1 barrier/step, fp32 + residual
// epilogue. 512 blocks = 2/CU.
// ---------------------------------------------------------------------------
__global__ __launch_bounds__(256, 3) void out_proj(
    const ushortT* __restrict__ Wob, const ushortT* __restrict__ Ot,
    const float* __restrict__ bo, float* __restrict__ Y,
    const float* __restrict__ residual)
{
    __shared__ __align__(16) ushortT As[2 * 64 * 64];
    __shared__ __align__(16) ushortT Bs[2 * 128 * 64];
    const int b = blockIdx.z;
    const int n0 = blockIdx.x * 128, m0 = blockIdx.y * 64;
    const int tid  = threadIdx.x;
    const int wave = tid >> 6, lane = tid & 63;
    const int quad = lane >> 4, l16 = lane & 15;
    const int wm = (wave & 1) * 32, wn = (wave >> 1) * 64;

    const ushortT* Wblk = Wob + (size_t)m0 * CH;
    const ushortT* Xblk = Ot + ((size_t)b * NPIX + n0) * CH;

    f32x4 acc[2][4];
#pragma unroll
    for (int i = 0; i < 2; ++i)
#pragma unroll
        for (int j = 0; j < 4; ++j) acc[i][j] = (f32x4){0.f, 0.f, 0.f, 0.f};

    stage_swz<64>(As, Wblk, CH, wave, lane);
    stage_swz<128>(Bs, Xblk, CH, wave, lane);
    __syncthreads();

    int buf = 0;
    for (int s = 0; s < 8; ++s) {
        if (s < 7) {
            stage_swz<64>(As + (buf ^ 1) * 64 * 64,  Wblk + (s + 1) * 64, CH, wave, lane);
            stage_swz<128>(Bs + (buf ^ 1) * 128 * 64, Xblk + (s + 1) * 64, CH, wave, lane);
        }
        const ushortT* A  = As + buf * 64 * 64;
        const ushortT* Bp = Bs + buf * 128 * 64;
        frag8 af[2][2], bfr[4][2];
#pragma unroll
        for (int ks = 0; ks < 2; ++ks) {
#pragma unroll
            for (int i = 0; i < 2; ++i)
                af[i][ks] = frd(A, wm + i * 16 + l16, ks * 4 + quad);
#pragma unroll
            for (int j = 0; j < 4; ++j)
                bfr[j][ks] = frd(Bp, wn + j * 16 + l16, ks * 4 + quad);
        }
#pragma unroll
        for (int ks = 0; ks < 2; ++ks)
#pragma unroll
            for (int i = 0; i < 2; ++i)
#pragma unroll
                for (int j = 0; j < 4; ++j)
                    acc[i][j] = __builtin_amdgcn_mfma_f32_16x16x32_bf16(
                        af[i][ks], bfr[j][ks], acc[i][j], 0, 0, 0);
        __syncthreads();
        buf ^= 1;
    }

#pragma unroll
    for (int i = 0; i < 2; ++i) {
        const int om0 = m0 + wm + i * 16 + quad * 4;
#pragma unroll
        for (int j = 0; j < 4; ++j) {
            const int on = n0 + wn + j * 16 + l16;
#pragma unroll
            for (int r = 0; r < 4; ++r) {
                const int om = om0 + r;
                const size_t idx = ((size_t)b * CH + om) * NPIX + on;
                Y[idx] = acc[i][j][r] + bo[om] + residual[idx];
            }
        }
    }
}

// ---------------------------------------------------------------------------
// Flash attention — best-measured configuration (156.8 / 158.9 us total;
// rounds 12 / 5). 512 threads / 8 waves per block, wave owns 16 n-rows; grid
// (64,8) = 512 blocks = 2 blocks/CU. Structural variants all measured worse:
// LDS-traffic geometry (r6/r8: 173/174), counted-vmcnt pipeline (r11: 172.5,
// m141 scheduler-pinning lesson), split-KV 3-blocks/CU (r13: 169, partial-
// traffic + fixed-cost duplication). This is the plateau of this
// decomposition. K/V double-buffered via global_load_lds; one __syncthreads
// per tile; T5 setprio around MFMA clusters.
// ---------------------------------------------------------------------------
__global__ __launch_bounds__(512, 2) void attn_mfma(
    const ushortT* __restrict__ Qt, const ushortT* __restrict__ Kt,
    const ushortT* __restrict__ V, ushortT* __restrict__ Ot)
{
    __shared__ __align__(16) ushortT Ks[2][64 * 64];   // [m][d] swizzled
    __shared__ __align__(16) ushortT Vs[2][64 * 64];   // [d][m] swizzled
    __shared__ __align__(16) ushortT Ps[128 * 72];     // [n][m], wave-private rows
    const int bh = blockIdx.x;          // 0..63
    const int n0 = blockIdx.y * 128;
    const int b  = bh >> 3, h = bh & 7;
    const int tid  = threadIdx.x;
    const int wave = tid >> 6, lane = tid & 63;
    const int quad = lane >> 4, l16 = lane & 15;
    const size_t qrow  = (size_t)b * NPIX;
    const size_t vbase = ((size_t)b * CH + h * HD) * NPIX;
    const int nw = n0 + wave * 16;      // this wave's 16 query rows

    // Q fragments in registers, loaded once from global
    frag8 aq[2];   // [ks]
#pragma unroll
    for (int ks = 0; ks < 2; ++ks)
        aq[ks] = *(const frag8*)&Qt[(qrow + nw + l16) * CH
                                    + h * HD + ks * 32 + quad * 8];
    frag8 ones;
#pragma unroll
    for (int i = 0; i < 8; ++i) ones[i] = (short)0x3F80;   // bf16 1.0

    f32x4 oacc[4], lacc;
    lacc = (f32x4){0.f, 0.f, 0.f, 0.f};
#pragma unroll
    for (int dt = 0; dt < 4; ++dt) oacc[dt] = (f32x4){0.f, 0.f, 0.f, 0.f};

    // exp(s*0.125) == exp2(s * 0.125*log2(e)): fold scale+log2e into one mul
    const float SC2 = 0.18033688011112042f;

    stage_swz8(Ks[0], Kt + qrow * CH + h * HD, CH, wave, lane);
    stage_swz8(Vs[0], V + vbase, NPIX, wave, lane);
    __syncthreads();

    int buf = 0;
    for (int t = 0; t < NPIX / 64; ++t) {
        if (t + 1 < NPIX / 64) {   // async prefetch next K/V tile
            stage_swz8(Ks[buf ^ 1], Kt + (qrow + (t + 1) * 64) * CH + h * HD,
                       CH, wave, lane);
            stage_swz8(Vs[buf ^ 1], V + vbase + (t + 1) * 64, NPIX, wave, lane);
        }

        // S^T = K Q^T; P = exp2(S*SC2) packed 4-wide into Ps[n][m]
#pragma unroll
        for (int mt = 0; mt < 4; ++mt) {
            f32x4 st = (f32x4){0.f, 0.f, 0.f, 0.f};
            __builtin_amdgcn_s_setprio(1);
#pragma unroll
            for (int ks = 0; ks < 2; ++ks) {
                frag8 bk = frd(Ks[buf], mt * 16 + l16, ks * 4 + quad);
                st = __builtin_amdgcn_mfma_f32_16x16x32_bf16(bk, aq[ks], st, 0, 0, 0);
            }
            __builtin_amdgcn_s_setprio(0);
            ushort4 p;
            p.x = f2u(exp2f(st[0] * SC2)); p.y = f2u(exp2f(st[1] * SC2));
            p.z = f2u(exp2f(st[2] * SC2)); p.w = f2u(exp2f(st[3] * SC2));
            *(ushort4*)&Ps[(wave * 16 + l16) * 72 + mt * 16 + quad * 4] = p;
        }
        // Ps rows are wave-private: in-wave lgkmcnt ordering suffices, no barrier.

        frag8 ap[2];
#pragma unroll
        for (int ks = 0; ks < 2; ++ks)
            ap[ks] = *(const frag8*)&Ps[(wave * 16 + l16) * 72 + ks * 32 + quad * 8];

        __builtin_amdgcn_s_setprio(1);
        // l += P @ ones
#pragma unroll
        for (int ks = 0; ks < 2; ++ks)
            lacc = __builtin_amdgcn_mfma_f32_16x16x32_bf16(ap[ks], ones, lacc, 0, 0, 0);
        // O += P V
#pragma unroll
        for (int dt = 0; dt < 4; ++dt)
#pragma unroll
            for (int ks = 0; ks < 2; ++ks) {
                frag8 bv = frd(Vs[buf], dt * 16 + l16, ks * 4 + quad);
                oacc[dt] = __builtin_amdgcn_mfma_f32_16x16x32_bf16(ap[ks], bv, oacc[dt], 0, 0, 0);
            }
        __builtin_amdgcn_s_setprio(0);

        __syncthreads();   // drains vmcnt: next buffer staged; all waves done with cur
        buf ^= 1;
    }

    // epilogue: O_t[n][h*64+d] = oacc / l  (in-place over Qt block-local region)
#pragma unroll
    for (int r = 0; r < 4; ++r) {
        float inv = __builtin_amdgcn_rcpf(lacc[r]);
        int n = nw + quad * 4 + r;
#pragma unroll
        for (int dt = 0; dt < 4; ++dt)
            Ot[(qrow + n) * CH + h * HD + dt * 16 + l16] =
                f2u(oacc[dt][r] * inv);
    }
}

// Sentinel: ws too small -> zero output (absmax == max|ref| ~5.0, distinguishable)
__global__ void zero_out_kernel(float* o, int n) {
    int i = blockIdx.x * 256 + threadIdx.x;
    if (i < n) o[i] = 0.f;
}

extern "C" void kernel_launch(void* const* d_in, const int* in_sizes, int n_in,
                              void* d_out, int out_size, void* d_ws, size_t ws_size,
                              hipStream_t stream) {
    const float* self  = (const float*)d_in[0];
    const float* cross = (const float*)d_in[1];
    const float* Wq = (const float*)d_in[2];
    const float* bq = (const float*)d_in[3];
    const float* Wk = (const float*)d_in[4];
    const float* bk = (const float*)d_in[5];
    const float* Wv = (const float*)d_in[6];
    const float* bv = (const float*)d_in[7];
    const float* Wo = (const float*)d_in[8];
    const float* bo = (const float*)d_in[9];

    const size_t NELT = (size_t)B_ * CH * NPIX;   // 4,194,304
    const size_t WELT = (size_t)CH * CH;          //   262,144

    // ws: Qt(8M) | Kt(8M) | Vn(8M) | Wb x4 (2M)  = 26 MiB
    if (ws_size < (3 * NELT + 4 * WELT) * sizeof(ushortT)) {
        const size_t n = (size_t)B_ * CH * NPIX;
        zero_out_kernel<<<(int)((n + 255) / 256), 256, 0, stream>>>((float*)d_out, (int)n);
        return;
    }

    // d_out (16 MiB) doubles as scratch: [crossT 8MiB | selfT 8MiB]
    ushortT* crossT = (ushortT*)d_out;
    ushortT* selfT  = (ushortT*)d_out + NELT;
    ushortT* Qt  = (ushortT*)d_ws;            // [b][n][c]
    ushortT* Kt  = Qt + NELT;                 // [b][n][c]
    ushortT* Vn  = Kt + NELT;                 // [b][c][n]
    ushortT* Wb  = Vn + NELT;                 // 4x [512][512] bf16
    ushortT* Wqb = Wb;
    ushortT* Wkb = Wb + WELT;
    ushortT* Wvb = Wb + 2 * WELT;
    ushortT* Wob = Wb + 3 * WELT;

    dim3 bb(256);
    cvt_transpose<<<dim3(16, 8, 20), bb, 0, stream>>>(cross, self, crossT, selfT,
                                                      Wq, Wk, Wv, Wo, Wb);
    qkv_proj<<<dim3(8, 4, 24), bb, 0, stream>>>(Wqb, Wkb, Wvb, selfT, crossT,
                                                bq, bk, bv, Qt, Kt, Vn);
    attn_mfma<<<dim3(64, 8), dim3(512), 0, stream>>>(Qt, Kt, Vn, Qt);
    out_proj<<<dim3(8, 8, B_), bb, 0, stream>>>(Wob, Qt, bo, (float*)d_out, self);
}

// Round 15
// 156.011 us; speedup vs baseline: 1.0833x; 1.0185x over previous
//
#include <hip/hip_runtime.h>
#include <hip/hip_bf16.h>

#define B_    8
#define CH    512
#define NPIX  1024
#define HEADS 8
#define HD    64

typedef unsigned short ushortT;
typedef __attribute__((ext_vector_type(8))) short frag8;   // 8 bf16 (4 VGPRs)
typedef __attribute__((ext_vector_type(4))) float f32x4;   // MFMA C/D

__device__ __forceinline__ ushortT f2u(float f) {
    __hip_bfloat16 h = __float2bfloat16(f);
    return *(ushortT*)&h;
}
__device__ __forceinline__ unsigned pack2(float lo, float hi) {
    return (unsigned)f2u(lo) | ((unsigned)f2u(hi) << 16);
}

// Async global->LDS, 16B per lane. LDS dest is wave-uniform base + lane*16.
__device__ __forceinline__ void gload16(const ushortT* g, ushortT* lds) {
    __builtin_amdgcn_global_load_lds(
        (const __attribute__((address_space(1))) unsigned int*)g,
        (__attribute__((address_space(3))) unsigned int*)lds, 16, 0, 0);
}

// Stage R rows x 64 bf16 cols from global (row stride srow elems) into linear
// LDS [R][64] by 4 waves. XOR-swizzle: LDS(r, chunk) holds global(r, chunk^(r&7))
// [chunk = 16B]. Read of global (r,c) = LDS chunk c^(r&7) (T2, involution).
template<int R>
__device__ __forceinline__ void stage_swz(ushortT* lds, const ushortT* src,
                                          size_t srow, int wave, int lane) {
    const int rl = lane >> 3, ch = lane & 7;
#pragma unroll
    for (int j = 0; j < R / 32; ++j) {
        const int r = wave * (R / 4) + j * 8 + rl;
        gload16(src + (size_t)r * srow + ((ch ^ (r & 7)) * 8),
                lds + (wave * (R / 4) + j * 8) * 64);
    }
}

// Same, for 8-wave (512-thread) blocks staging a 64-row tile: 1 gload16/wave.
__device__ __forceinline__ void stage_swz8(ushortT* lds, const ushortT* src,
                                           size_t srow, int wave, int lane) {
    const int rl = lane >> 3, ch = lane & 7;
    const int r = wave * 8 + rl;
    gload16(src + (size_t)r * srow + ((ch ^ (r & 7)) * 8),
            lds + (wave * 8) * 64);
}

// Read one 16B fragment of global (row, kq*8..kq*8+7) from a swizzled tile.
__device__ __forceinline__ frag8 frd(const ushortT* lds, int row, int kq) {
    return *(const frag8*)&lds[row * 64 + ((kq ^ (row & 7)) * 8)];
}

// Both fp32->bf16 transposes + all 4 weight conversions in one launch.
// z in [0,16): transpose (b = z&7, which = z>>3).  z in [16,20): W cvt.
__global__ __launch_bounds__(256) void cvt_transpose(
    const float* __restrict__ Xc, const float* __restrict__ Xs,
    ushortT* __restrict__ XTc, ushortT* __restrict__ XTs,
    const float* __restrict__ Wq, const float* __restrict__ Wk,
    const float* __restrict__ Wv, const float* __restrict__ Wo,
    ushortT* __restrict__ Wb)
{
    if (blockIdx.z >= 16) {   // weight fp32 -> bf16, once
        const int w = blockIdx.z - 16;
        const float* Wsrc = (w == 0) ? Wq : (w == 1) ? Wk : (w == 2) ? Wv : Wo;
        ushortT* Wdst = Wb + (size_t)w * CH * CH;
        const int base = (blockIdx.y * 16 + blockIdx.x) * 2048 + threadIdx.x * 8;
        float4 f0 = *(const float4*)&Wsrc[base];
        float4 f1 = *(const float4*)&Wsrc[base + 4];
        ushortT t[8];
        t[0]=f2u(f0.x); t[1]=f2u(f0.y); t[2]=f2u(f0.z); t[3]=f2u(f0.w);
        t[4]=f2u(f1.x); t[5]=f2u(f1.y); t[6]=f2u(f1.z); t[7]=f2u(f1.w);
        *(uint4*)&Wdst[base] = *(uint4*)t;
        return;
    }
    __shared__ __align__(16) ushortT T[64 * 72];   // [n][c], stride 72
    const int n0 = blockIdx.x * 64;
    const int c0 = blockIdx.y * 64;
    const int b  = blockIdx.z & 7;
    const int which = blockIdx.z >> 3;
    const float* X = which ? Xs : Xc;
    ushortT* XT    = which ? XTs : XTc;
    const int tid = threadIdx.x;
#pragma unroll
    for (int it = 0; it < 2; ++it) {
        int idx = tid + it * 256;          // 512 items: 32 c-pairs x 16 n-quads
        int cp = idx >> 4;
        int nq = (idx & 15) * 4;
        const float* s0 = &X[((size_t)b * CH + c0 + 2 * cp) * NPIX + n0 + nq];
        float4 f0 = *(const float4*)s0;
        float4 f1 = *(const float4*)(s0 + NPIX);
        *(unsigned*)&T[(nq + 0) * 72 + 2 * cp] = pack2(f0.x, f1.x);
        *(unsigned*)&T[(nq + 1) * 72 + 2 * cp] = pack2(f0.y, f1.y);
        *(unsigned*)&T[(nq + 2) * 72 + 2 * cp] = pack2(f0.z, f1.z);
        *(unsigned*)&T[(nq + 3) * 72 + 2 * cp] = pack2(f0.w, f1.w);
    }
    __syncthreads();
#pragma unroll
    for (int it = 0; it < 2; ++it) {
        int idx = tid + it * 256;
        int n  = idx >> 3;
        int cq = (idx & 7) * 8;
        *(uint4*)&XT[((size_t)b * NPIX + n0 + n) * CH + c0 + cq] =
            *(const uint4*)&T[n * 72 + cq];
    }
}

// ---------------------------------------------------------------------------
// m97-structure GEMM: block tile 128m x 128n, BK=64, single 32KB LDS buffer,
// 2 barriers per K-step. 4 waves, each 64x64 output. 3 blocks/CU.
// MODE 0: bf16 natural [b][o][n]; MODE 1: bf16 transposed [b][n][o].
// ---------------------------------------------------------------------------
template<int MODE>
__device__ __forceinline__ void proj128_body(
    ushortT* As, ushortT* Bs,   // [128*64] each, swizzled
    const ushortT* __restrict__ Wb, const ushortT* __restrict__ XT,
    const float* __restrict__ bias, void* __restrict__ Yv,
    int b, int n0, int m0)
{
    const int tid  = threadIdx.x;
    const int wave = tid >> 6, lane = tid & 63;
    const int quad = lane >> 4, l16 = lane & 15;
    const int wm = (wave & 1) * 64, wn = (wave >> 1) * 64;

    const ushortT* Wblk = Wb + (size_t)m0 * CH;
    const ushortT* Xblk = XT + ((size_t)b * NPIX + n0) * CH;

    f32x4 acc[4][4];
#pragma unroll
    for (int i = 0; i < 4; ++i)
#pragma unroll
        for (int j = 0; j < 4; ++j) acc[i][j] = (f32x4){0.f, 0.f, 0.f, 0.f};

    for (int s = 0; s < 8; ++s) {
        if (s) __syncthreads();               // all waves done reading buffer
        stage_swz<128>(As, Wblk + s * 64, CH, wave, lane);
        stage_swz<128>(Bs, Xblk + s * 64, CH, wave, lane);
        __syncthreads();                      // drains vmcnt: tile staged
#pragma unroll
        for (int ks = 0; ks < 2; ++ks) {
            frag8 af[4], bf[4];
#pragma unroll
            for (int i = 0; i < 4; ++i)
                af[i] = frd(As, wm + i * 16 + l16, ks * 4 + quad);
#pragma unroll
            for (int j = 0; j < 4; ++j)
                bf[j] = frd(Bs, wn + j * 16 + l16, ks * 4 + quad);
#pragma unroll
            for (int i = 0; i < 4; ++i)
#pragma unroll
                for (int j = 0; j < 4; ++j)
                    acc[i][j] = __builtin_amdgcn_mfma_f32_16x16x32_bf16(
                        af[i], bf[j], acc[i][j], 0, 0, 0);
        }
    }

#pragma unroll
    for (int i = 0; i < 4; ++i) {
        const int om0 = m0 + wm + i * 16 + quad * 4;
#pragma unroll
        for (int j = 0; j < 4; ++j) {
            const int on = n0 + wn + j * 16 + l16;
            if (MODE == 1) {
                ushort4 v;
                v.x = f2u(acc[i][j][0] + bias[om0 + 0]);
                v.y = f2u(acc[i][j][1] + bias[om0 + 1]);
                v.z = f2u(acc[i][j][2] + bias[om0 + 2]);
                v.w = f2u(acc[i][j][3] + bias[om0 + 3]);
                *(ushort4*)&((ushortT*)Yv)[((size_t)b * NPIX + on) * CH + om0] = v;
            } else {
#pragma unroll
                for (int r = 0; r < 4; ++r) {
                    const int om = om0 + r;
                    ((ushortT*)Yv)[((size_t)b * CH + om) * NPIX + on] =
                        f2u(acc[i][j][r] + bias[om]);
                }
            }
        }
    }
}

// Fused Q+K+V projections. z = which*8 + b; 0=Q(selfT),1=K(crossT),2=V(crossT).
__global__ __launch_bounds__(256, 3) void qkv_proj(
    const ushortT* __restrict__ Wqb, const ushortT* __restrict__ Wkb,
    const ushortT* __restrict__ Wvb,
    const ushortT* __restrict__ selfT, const ushortT* __restrict__ crossT,
    const float* __restrict__ bq, const float* __restrict__ bk,
    const float* __restrict__ bv,
    ushortT* __restrict__ Qt, ushortT* __restrict__ Kt, ushortT* __restrict__ Vn)
{
    __shared__ __align__(16) ushortT As[128 * 64];
    __shared__ __align__(16) ushortT Bs[128 * 64];
    const int which = blockIdx.z >> 3;
    const int b     = blockIdx.z & 7;
    const int n0 = blockIdx.x * 128, m0 = blockIdx.y * 128;
    if (which == 2)
        proj128_body<0>(As, Bs, Wvb, crossT, bv, Vn, b, n0, m0);
    else if (which == 1)
        proj128_body<1>(As, Bs, Wkb, crossT, bk, Kt, b, n0, m0);
    else
        proj128_body<1>(As, Bs, Wqb, selfT, bq, Qt, b, n0, m0);
}

// ---------------------------------------------------------------------------
// out_proj: 64m x 128n, double-buffered, 1 barrier/step, fp32 + residual
// epilogue. 512 blocks = 2/CU.
// ---------------------------------------------------------------------------
__global__ __launch_bounds__(256, 3) void out_proj(
    const ushortT* __restrict__ Wob, const ushortT* __restrict__ Ot,
    const float* __restrict__ bo, float* __restrict__ Y,
    const float* __restrict__ residual)
{
    __shared__ __align__(16) ushortT As[2 * 64 * 64];
    __shared__ __align__(16) ushortT Bs[2 * 128 * 64];
    const int b = blockIdx.z;
    const int n0 = blockIdx.x * 128, m0 = blockIdx.y * 64;
    const int tid  = threadIdx.x;
    const int wave = tid >> 6, lane = tid & 63;
    const int quad = lane >> 4, l16 = lane & 15;
    const int wm = (wave & 1) * 32, wn = (wave >> 1) * 64;

    const ushortT* Wblk = Wob + (size_t)m0 * CH;
    const ushortT* Xblk = Ot + ((size_t)b * NPIX + n0) * CH;

    f32x4 acc[2][4];
#pragma unroll
    for (int i = 0; i < 2; ++i)
#pragma unroll
        for (int j = 0; j < 4; ++j) acc[i][j] = (f32x4){0.f, 0.f, 0.f, 0.f};

    stage_swz<64>(As, Wblk, CH, wave, lane);
    stage_swz<128>(Bs, Xblk, CH, wave, lane);
    __syncthreads();

    int buf = 0;
    for (int s = 0; s < 8; ++s) {
        if (s < 7) {
            stage_swz<64>(As + (buf ^ 1) * 64 * 64,  Wblk + (s + 1) * 64, CH, wave, lane);
            stage_swz<128>(Bs + (buf ^ 1) * 128 * 64, Xblk + (s + 1) * 64, CH, wave, lane);
        }
        const ushortT* A  = As + buf * 64 * 64;
        const ushortT* Bp = Bs + buf * 128 * 64;
        frag8 af[2][2], bfr[4][2];
#pragma unroll
        for (int ks = 0; ks < 2; ++ks) {
#pragma unroll
            for (int i = 0; i < 2; ++i)
                af[i][ks] = frd(A, wm + i * 16 + l16, ks * 4 + quad);
#pragma unroll
            for (int j = 0; j < 4; ++j)
                bfr[j][ks] = frd(Bp, wn + j * 16 + l16, ks * 4 + quad);
        }
#pragma unroll
        for (int ks = 0; ks < 2; ++ks)
#pragma unroll
            for (int i = 0; i < 2; ++i)
#pragma unroll
                for (int j = 0; j < 4; ++j)
                    acc[i][j] = __builtin_amdgcn_mfma_f32_16x16x32_bf16(
                        af[i][ks], bfr[j][ks], acc[i][j], 0, 0, 0);
        __syncthreads();
        buf ^= 1;
    }

#pragma unroll
    for (int i = 0; i < 2; ++i) {
        const int om0 = m0 + wm + i * 16 + quad * 4;
#pragma unroll
        for (int j = 0; j < 4; ++j) {
            const int on = n0 + wn + j * 16 + l16;
#pragma unroll
            for (int r = 0; r < 4; ++r) {
                const int om = om0 + r;
                const size_t idx = ((size_t)b * CH + om) * NPIX + on;
                Y[idx] = acc[i][j][r] + bo[om] + residual[idx];
            }
        }
    }
}

// ---------------------------------------------------------------------------
// Flash attention — best-measured configuration (156.8 / 158.9 / 158.9 us
// total; rounds 12 / 5 / 14). 512 threads / 8 waves per block, wave owns 16
// n-rows; grid (64,8) = 512 blocks = 2 blocks/CU. Structural variants all
// measured worse: LDS-traffic geometry (r6/r8: 173/174), counted-vmcnt
// pipeline (r11: 172.5, m141 scheduler-pinning lesson), split-KV 3-blocks/CU
// (r13: 169). This is the plateau of this decomposition. K/V double-buffered
// via global_load_lds; one __syncthreads per tile; T5 setprio.
// ---------------------------------------------------------------------------
__global__ __launch_bounds__(512, 2) void attn_mfma(
    const ushortT* __restrict__ Qt, const ushortT* __restrict__ Kt,
    const ushortT* __restrict__ V, ushortT* __restrict__ Ot)
{
    __shared__ __align__(16) ushortT Ks[2][64 * 64];   // [m][d] swizzled
    __shared__ __align__(16) ushortT Vs[2][64 * 64];   // [d][m] swizzled
    __shared__ __align__(16) ushortT Ps[128 * 72];     // [n][m], wave-private rows
    const int bh = blockIdx.x;          // 0..63
    const int n0 = blockIdx.y * 128;
    const int b  = bh >> 3, h = bh & 7;
    const int tid  = threadIdx.x;
    const int wave = tid >> 6, lane = tid & 63;
    const int quad = lane >> 4, l16 = lane & 15;
    const size_t qrow  = (size_t)b * NPIX;
    const size_t vbase = ((size_t)b * CH + h * HD) * NPIX;
    const int nw = n0 + wave * 16;      // this wave's 16 query rows

    // Q fragments in registers, loaded once from global
    frag8 aq[2];   // [ks]
#pragma unroll
    for (int ks = 0; ks < 2; ++ks)
        aq[ks] = *(const frag8*)&Qt[(qrow + nw + l16) * CH
                                    + h * HD + ks * 32 + quad * 8];
    frag8 ones;
#pragma unroll
    for (int i = 0; i < 8; ++i) ones[i] = (short)0x3F80;   // bf16 1.0

    f32x4 oacc[4], lacc;
    lacc = (f32x4){0.f, 0.f, 0.f, 0.f};
#pragma unroll
    for (int dt = 0; dt < 4; ++dt) oacc[dt] = (f32x4){0.f, 0.f, 0.f, 0.f};

    // exp(s*0.125) == exp2(s * 0.125*log2(e)): fold scale+log2e into one mul
    const float SC2 = 0.18033688011112042f;

    stage_swz8(Ks[0], Kt + qrow * CH + h * HD, CH, wave, lane);
    stage_swz8(Vs[0], V + vbase, NPIX, wave, lane);
    __syncthreads();

    int buf = 0;
    for (int t = 0; t < NPIX / 64; ++t) {
        if (t + 1 < NPIX / 64) {   // async prefetch next K/V tile
            stage_swz8(Ks[buf ^ 1], Kt + (qrow + (t + 1) * 64) * CH + h * HD,
                       CH, wave, lane);
            stage_swz8(Vs[buf ^ 1], V + vbase + (t + 1) * 64, NPIX, wave, lane);
        }

        // S^T = K Q^T; P = exp2(S*SC2) packed 4-wide into Ps[n][m]
#pragma unroll
        for (int mt = 0; mt < 4; ++mt) {
            f32x4 st = (f32x4){0.f, 0.f, 0.f, 0.f};
            __builtin_amdgcn_s_setprio(1);
#pragma unroll
            for (int ks = 0; ks < 2; ++ks) {
                frag8 bk = frd(Ks[buf], mt * 16 + l16, ks * 4 + quad);
                st = __builtin_amdgcn_mfma_f32_16x16x32_bf16(bk, aq[ks], st, 0, 0, 0);
            }
            __builtin_amdgcn_s_setprio(0);
            ushort4 p;
            p.x = f2u(exp2f(st[0] * SC2)); p.y = f2u(exp2f(st[1] * SC2));
            p.z = f2u(exp2f(st[2] * SC2)); p.w = f2u(exp2f(st[3] * SC2));
            *(ushort4*)&Ps[(wave * 16 + l16) * 72 + mt * 16 + quad * 4] = p;
        }
        // Ps rows are wave-private: in-wave lgkmcnt ordering suffices, no barrier.

        frag8 ap[2];
#pragma unroll
        for (int ks = 0; ks < 2; ++ks)
            ap[ks] = *(const frag8*)&Ps[(wave * 16 + l16) * 72 + ks * 32 + quad * 8];

        __builtin_amdgcn_s_setprio(1);
        // l += P @ ones
#pragma unroll
        for (int ks = 0; ks < 2; ++ks)
            lacc = __builtin_amdgcn_mfma_f32_16x16x32_bf16(ap[ks], ones, lacc, 0, 0, 0);
        // O += P V
#pragma unroll
        for (int dt = 0; dt < 4; ++dt)
#pragma unroll
            for (int ks = 0; ks < 2; ++ks) {
                frag8 bv = frd(Vs[buf], dt * 16 + l16, ks * 4 + quad);
                oacc[dt] = __builtin_amdgcn_mfma_f32_16x16x32_bf16(ap[ks], bv, oacc[dt], 0, 0, 0);
            }
        __builtin_amdgcn_s_setprio(0);

        __syncthreads();   // drains vmcnt: next buffer staged; all waves done with cur
        buf ^= 1;
    }

    // epilogue: O_t[n][h*64+d] = oacc / l  (in-place over Qt block-local region)
#pragma unroll
    for (int r = 0; r < 4; ++r) {
        float inv = __builtin_amdgcn_rcpf(lacc[r]);
        int n = nw + quad * 4 + r;
#pragma unroll
        for (int dt = 0; dt < 4; ++dt)
            Ot[(qrow + n) * CH + h * HD + dt * 16 + l16] =
                f2u(oacc[dt][r] * inv);
    }
}

// Sentinel: ws too small -> zero output (absmax == max|ref| ~5.0, distinguishable)
__global__ void zero_out_kernel(float* o, int n) {
    int i = blockIdx.x * 256 + threadIdx.x;
    if (i < n) o[i] = 0.f;
}

extern "C" void kernel_launch(void* const* d_in, const int* in_sizes, int n_in,
                              void* d_out, int out_size, void* d_ws, size_t ws_size,
                              hipStream_t stream) {
    const float* self  = (const float*)d_in[0];
    const float* cross = (const float*)d_in[1];
    const float* Wq = (const float*)d_in[2];
    const float* bq = (const float*)d_in[3];
    const float* Wk = (const float*)d_in[4];
    const float* bk = (const float*)d_in[5];
    const float* Wv = (const float*)d_in[6];
    const float* bv = (const float*)d_in[7];
    const float* Wo = (const float*)d_in[8];
    const float* bo = (const float*)d_in[9];

    const size_t NELT = (size_t)B_ * CH * NPIX;   // 4,194,304
    const size_t WELT = (size_t)CH * CH;          //   262,144

    // ws: Qt(8M) | Kt(8M) | Vn(8M) | Wb x4 (2M)  = 26 MiB
    if (ws_size < (3 * NELT + 4 * WELT) * sizeof(ushortT)) {
        const size_t n = (size_t)B_ * CH * NPIX;
        zero_out_kernel<<<(int)((n + 255) / 256), 256, 0, stream>>>((float*)d_out, (int)n);
        return;
    }

    // d_out (16 MiB) doubles as scratch: [crossT 8MiB | selfT 8MiB]
    ushortT* crossT = (ushortT*)d_out;
    ushortT* selfT  = (ushortT*)d_out + NELT;
    ushortT* Qt  = (ushortT*)d_ws;            // [b][n][c]
    ushortT* Kt  = Qt + NELT;                 // [b][n][c]
    ushortT* Vn  = Kt + NELT;                 // [b][c][n]
    ushortT* Wb  = Vn + NELT;                 // 4x [512][512] bf16
    ushortT* Wqb = Wb;
    ushortT* Wkb = Wb + WELT;
    ushortT* Wvb = Wb + 2 * WELT;
    ushortT* Wob = Wb + 3 * WELT;

    dim3 bb(256);
    cvt_transpose<<<dim3(16, 8, 20), bb, 0, stream>>>(cross, self, crossT, selfT,
                                                      Wq, Wk, Wv, Wo, Wb);
    qkv_proj<<<dim3(8, 4, 24), bb, 0, stream>>>(Wqb, Wkb, Wvb, selfT, crossT,
                                                bq, bk, bv, Qt, Kt, Vn);
    attn_mfma<<<dim3(64, 8), dim3(512), 0, stream>>>(Qt, Kt, Vn, Qt);
    out_proj<<<dim3(8, 8, B_), bb, 0, stream>>>(Wob, Qt, bo, (float*)d_out, self);
}